// Round 10
// baseline (114.359 us; speedup 1.0000x reference)
//
#include <hip/hip_runtime.h>
#include <math.h>

#define N_NODES_C 50000
#define N_EDGES_C 1600000
#define EPB3 4096
#define NBLK_E3 391                       // ceil(1.6M / 4096); last block has 2560 edges
#define NBLK_N 196                        // (50000+255)>>8
#define TBL 256                           // radial table over r in [0,3]

#define NREG 25                           // col buckets of 2048 nodes (50000/2048 -> 25)
#define RSH 11
#define RNODES 2048
#define CAPL 17                           // 131072 slots/region (mean ~64K)
#define NCHG 32                           // gather chunks per bucket

// Quantization q=1/1024 (validated R5: digit-exact u64 accumulation).
#define QSCALE 1024.0f
#define QINV   (1.0f / 1024.0f)

// ---------- per-block dtype detect ----------
__device__ __forceinline__ int detect_is64_block(const void* eidx, int t, int* lds_flag) {
    if (t < 64) {
        const long long* p = (const long long*)eidx;
        bool ok = true;
        for (int k = 0; k < 4; ++k) {
            long long v = p[t * 4 + k];
            ok &= (v >= 0 && v < (long long)N_NODES_C);
        }
        unsigned long long m = __ballot(ok);
        if (t == 0) *lds_flag = (m == ~0ull) ? 1 : 0;
    }
    __syncthreads();
    return *lds_flag;
}

__device__ __forceinline__ int load_col(const void* eidx, int is64, int e) {
    return is64 ? (int)((const long long*)eidx)[N_EDGES_C + e]
                : ((const int*)eidx)[N_EDGES_C + e];
}
__device__ __forceinline__ int load_row(const void* eidx, int is64, int e) {
    return is64 ? (int)((const long long*)eidx)[e]
                : ((const int*)eidx)[e];
}

// ---------- exact edge math (fallback path only; validated R5-R11) ----------
__device__ __forceinline__ void edge_quant(const float* __restrict__ f1,
                                           const float* __restrict__ pos,
                                           const float* __restrict__ w1s,
                                           const float* __restrict__ W2,
                                           int row, int col, int v[4]) {
    v[0] = v[1] = v[2] = v[3] = 0;
    float px = pos[row * 3 + 0] - pos[col * 3 + 0];
    float py = pos[row * 3 + 1] - pos[col * 3 + 1];
    float pz = pos[row * 3 + 2] - pos[col * 3 + 2];
    float r2 = px * px + py * py + pz * pz;
    float r = sqrtf(fmaxf(r2, 1e-12f));
    float inv_r = 1.0f / r;
    float ux = px * inv_r, uy = py * inv_r, uz = pz * inv_r;
    const float SQ3 = 1.7320508075688772f;
    float yv0 = SQ3 * uy, yv1 = SQ3 * uz, yv2 = SQ3 * ux;   // sh perm [1,2,0]

    const float C = 8.433573069075486f;  // 1.14136 * e^2
    float tt = r * (11.0f / 3.0f);
    int k1 = (int)tt;
    float d = tt - (float)k1;
    float e0 = 0.f, e1 = 0.f;
    int b0 = 0, b1 = 0;
    if (k1 >= 1 && k1 <= 10) {
        b0 = k1 - 1;
        e0 = C * __expf(-1.0f / (1.0f + d) - 1.0f / (1.0f - d));
    }
    int k2 = k1 + 1;
    if (k2 <= 10 && d > 0.f) {
        b1 = k2 - 1;
        float d2 = d - 1.0f;
        e1 = C * __expf(-1.0f / (1.0f + d2) - 1.0f / (1.0f - d2));
    }
    if (e0 == 0.f && e1 == 0.f) return;

    const float* r0 = &w1s[b0 * 68];
    const float* r1 = &w1s[b1 * 68];
    float w0 = 0.f, w1a = 0.f, w2a = 0.f, w3 = 0.f, w4 = 0.f;
#pragma unroll
    for (int j = 0; j < 64; j += 4) {
        float4 a = *(const float4*)(r0 + j);
        float4 b = *(const float4*)(r1 + j);
        float h0 = fmaxf(e0 * a.x + e1 * b.x, 0.f);
        float h1 = fmaxf(e0 * a.y + e1 * b.y, 0.f);
        float h2 = fmaxf(e0 * a.z + e1 * b.z, 0.f);
        float h3 = fmaxf(e0 * a.w + e1 * b.w, 0.f);
        w0  += h0 * W2[(j + 0) * 5 + 0] + h1 * W2[(j + 1) * 5 + 0] + h2 * W2[(j + 2) * 5 + 0] + h3 * W2[(j + 3) * 5 + 0];
        w1a += h0 * W2[(j + 0) * 5 + 1] + h1 * W2[(j + 1) * 5 + 1] + h2 * W2[(j + 2) * 5 + 1] + h3 * W2[(j + 3) * 5 + 1];
        w2a += h0 * W2[(j + 0) * 5 + 2] + h1 * W2[(j + 1) * 5 + 2] + h2 * W2[(j + 2) * 5 + 2] + h3 * W2[(j + 3) * 5 + 2];
        w3  += h0 * W2[(j + 0) * 5 + 3] + h1 * W2[(j + 1) * 5 + 3] + h2 * W2[(j + 2) * 5 + 3] + h3 * W2[(j + 3) * 5 + 3];
        w4  += h0 * W2[(j + 0) * 5 + 4] + h1 * W2[(j + 1) * 5 + 4] + h2 * W2[(j + 2) * 5 + 4] + h3 * W2[(j + 3) * 5 + 4];
    }
    const float SC = 0.05590169943749474f;  // sqrt(2/10)/8
    w0 *= SC; w1a *= SC; w2a *= SC; w3 *= SC; w4 *= SC;

    float4 x = *(const float4*)(f1 + row * 4);
    float x0 = x.x, xv0 = x.y, xv1 = x.z, xv2 = x.w;

    const float INV_S3 = 0.5773502691896258f;
    const float INV_S6 = 0.4082482904638631f;
    const float SQH    = 0.7071067811865476f;
    const float INV_SQRT_NN = 0.17677669529663687f;  // 1/sqrt(32)

    float dotxy = xv0 * yv0 + xv1 * yv1 + xv2 * yv2;
    float out0 = SQH * (w0 * x0 + w3 * dotxy * INV_S3) * INV_SQRT_NN;
    float cx0 = xv1 * yv2 - xv2 * yv1;
    float cx1 = xv2 * yv0 - xv0 * yv2;
    float cx2 = xv0 * yv1 - xv1 * yv0;
    float o1 = (w1a * x0 * yv0 * INV_S3 + w2a * xv0 * INV_S3 + w4 * cx0 * INV_S6) * INV_SQRT_NN;
    float o2 = (w1a * x0 * yv1 * INV_S3 + w2a * xv1 * INV_S3 + w4 * cx1 * INV_S6) * INV_SQRT_NN;
    float o3 = (w1a * x0 * yv2 * INV_S3 + w2a * xv2 * INV_S3 + w4 * cx2 * INV_S6) * INV_SQRT_NN;

    v[0] = min(8191, max(-8191, (int)rintf(out0 * QSCALE)));
    v[1] = min(8191, max(-8191, (int)rintf(o1   * QSCALE)));
    v[2] = min(8191, max(-8191, (int)rintf(o2   * QSCALE)));
    v[3] = min(8191, max(-8191, (int)rintf(o3   * QSCALE)));
}

// ---------- edge math -> packed digit sum (identical ops to validated path) ----------
__device__ __forceinline__ unsigned long long edge_q(
        float prx, float pry, float prz, float4 xx,
        float pcx, float pcy, float pcz,
        const float* tC0, const float* tC1, const float* tC2,
        const float* tC3, const float* tC4) {
    float px = prx - pcx;
    float py = pry - pcy;
    float pz = prz - pcz;
    float r2 = px * px + py * py + pz * pz;
    float r = sqrtf(fmaxf(r2, 1e-12f));
    float inv_r = 1.0f / r;
    // unit vector, sh-permuted [1,2,0]: uv = (uy, uz, ux)
    float uv0 = py * inv_r, uv1 = pz * inv_r, uv2 = px * inv_r;

    float ft = fminf(r * (255.0f / 3.0f), 255.0f);
    int idx = min((int)ft, TBL - 2);
    float fr = ft - (float)idx;
    float c0 = fmaf(fr, tC0[idx + 1] - tC0[idx], tC0[idx]);
    float c1 = fmaf(fr, tC1[idx + 1] - tC1[idx], tC1[idx]);
    float c2 = fmaf(fr, tC2[idx + 1] - tC2[idx], tC2[idx]);
    float c3 = fmaf(fr, tC3[idx + 1] - tC3[idx], tC3[idx]);
    float c4 = fmaf(fr, tC4[idx + 1] - tC4[idx], tC4[idx]);

    float x0 = xx.x, xv0 = xx.y, xv1 = xx.z, xv2 = xx.w;

    float dotxy = xv0 * uv0 + xv1 * uv1 + xv2 * uv2;
    float out0 = c0 * x0 + c3 * dotxy;
    float cx0 = xv1 * uv2 - xv2 * uv1;
    float cx1 = xv2 * uv0 - xv0 * uv2;
    float cx2 = xv0 * uv1 - xv1 * uv0;
    float c1x = c1 * x0;
    float o1 = c1x * uv0 + c2 * xv0 + c4 * cx0;
    float o2 = c1x * uv1 + c2 * xv1 + c4 * cx1;
    float o3 = c1x * uv2 + c2 * xv2 + c4 * cx2;

    int v0 = min(8191, max(-8191, (int)rintf(out0 * QSCALE)));
    int v1 = min(8191, max(-8191, (int)rintf(o1 * QSCALE)));
    int v2 = min(8191, max(-8191, (int)rintf(o2 * QSCALE)));
    int v3 = min(8191, max(-8191, (int)rintf(o3 * QSCALE)));

    return (unsigned long long)((long long)v0 + ((long long)v1 << 16)
         + ((long long)v2 << 32) + ((long long)v3 << 48));
}

// ---------- pass 1: MATH-FREE binning scatter (unchanged from R9) ----------
__global__ __launch_bounds__(1024)
void binscatter_kernel(const float* __restrict__ f1, const float* __restrict__ pos,
                       const float* __restrict__ W1, const float* __restrict__ W2,
                       const void* __restrict__ eidx,
                       unsigned* __restrict__ gOff,
                       unsigned* __restrict__ rcG,
                       float* __restrict__ nodeq,
                       float* __restrict__ tG) {
    __shared__ unsigned rcbuf[EPB3];         // 16 KB
    __shared__ unsigned stageRc[EPB3];       // 16 KB; first 2.7 KB aliased as w1s (block 0 only)
    __shared__ unsigned histB[4][32];        // 4-bank histogram
    __shared__ unsigned gBaseS[32];
    __shared__ unsigned localBaseS[32];
    __shared__ unsigned cursorLocS[32];
    __shared__ int flag_s;
    const int t = threadIdx.x;
    float* w1s = (float*)stageRc;            // safe: table build done before phase C writes stageRc
    if (blockIdx.x == 0) {
        for (int i = t; i < 640; i += 1024) w1s[(i >> 6) * 68 + (i & 63)] = W1[i];
    }
    if (t < 128) histB[t >> 5][t & 31] = 0u;
    const int is64 = detect_is64_block(eidx, t, &flag_s);  // includes __syncthreads

    if (blockIdx.x == 0 && t < TBL) {
        // ---- build table entry t (validated R12, bit-identical) ----
        float tt = (float)t * (11.0f / 255.0f);
        int k1 = (int)tt;
        float d = tt - (float)k1;
        const float C = 8.433573069075486f;  // 1.14136 * e^2
        float e0 = 0.f, e1 = 0.f;
        int b0 = 0, b1 = 0;
        if (k1 >= 1 && k1 <= 10) {
            b0 = k1 - 1;
            e0 = C * __expf(-1.0f / (1.0f + d) - 1.0f / (1.0f - d));
        }
        int k2 = k1 + 1;
        if (k2 <= 10 && d > 0.f) {
            b1 = k2 - 1;
            float d2 = d - 1.0f;
            e1 = C * __expf(-1.0f / (1.0f + d2) - 1.0f / (1.0f - d2));
        }
        float w0 = 0.f, w1 = 0.f, w2 = 0.f, w3 = 0.f, w4 = 0.f;
        const float* r0 = &w1s[b0 * 68];
        const float* r1 = &w1s[b1 * 68];
#pragma unroll
        for (int j = 0; j < 64; j += 4) {
            float4 a = *(const float4*)(r0 + j);
            float4 b = *(const float4*)(r1 + j);
            float h0 = fmaxf(e0 * a.x + e1 * b.x, 0.f);
            float h1 = fmaxf(e0 * a.y + e1 * b.y, 0.f);
            float h2 = fmaxf(e0 * a.z + e1 * b.z, 0.f);
            float h3 = fmaxf(e0 * a.w + e1 * b.w, 0.f);
            w0 += h0 * W2[(j + 0) * 5 + 0] + h1 * W2[(j + 1) * 5 + 0] + h2 * W2[(j + 2) * 5 + 0] + h3 * W2[(j + 3) * 5 + 0];
            w1 += h0 * W2[(j + 0) * 5 + 1] + h1 * W2[(j + 1) * 5 + 1] + h2 * W2[(j + 2) * 5 + 1] + h3 * W2[(j + 3) * 5 + 1];
            w2 += h0 * W2[(j + 0) * 5 + 2] + h1 * W2[(j + 1) * 5 + 2] + h2 * W2[(j + 2) * 5 + 2] + h3 * W2[(j + 3) * 5 + 2];
            w3 += h0 * W2[(j + 0) * 5 + 3] + h1 * W2[(j + 1) * 5 + 3] + h2 * W2[(j + 2) * 5 + 3] + h3 * W2[(j + 3) * 5 + 3];
            w4 += h0 * W2[(j + 0) * 5 + 4] + h1 * W2[(j + 1) * 5 + 4] + h2 * W2[(j + 2) * 5 + 4] + h3 * W2[(j + 3) * 5 + 4];
        }
        const float SC  = 0.05590169943749474f;   // sqrt(2/10)/8
        const float ISN = 0.17677669529663687f;   // 1/sqrt(32)
        const float SQH = 0.7071067811865476f;
        const float INV_S3 = 0.5773502691896258f;
        const float INV_S6 = 0.4082482904638631f;
        const float SQ3 = 1.7320508075688772f;
        float base = SC * ISN;
        tG[0 * TBL + t] = SQH * base * w0;
        tG[1 * TBL + t] = base * w1;
        tG[2 * TBL + t] = INV_S3 * base * w2;
        tG[3 * TBL + t] = SQH * base * w3;
        tG[4 * TBL + t] = INV_S6 * SQ3 * base * w4;
    }

    const int e0b = blockIdx.x * EPB3;
    const int nedge = min(EPB3, N_EDGES_C - e0b);  // 4096 or 2560
    const int hb = (t >> 6) & 3;
    for (int i = t; i < nedge; i += 1024) {
        int row = load_row(eidx, is64, e0b + i);
        int col = load_col(eidx, is64, e0b + i);
        rcbuf[i] = ((unsigned)row << 16) | (unsigned)col;
        atomicAdd(&histB[hb][col >> RSH], 1u);
    }
    {
        int n = blockIdx.x * 1024 + t;
        if (n < N_NODES_C) {
            float4 f = *(const float4*)(f1 + 4 * n);
            float4 p;
            p.x = pos[3 * n + 0];
            p.y = pos[3 * n + 1];
            p.z = pos[3 * n + 2];
            p.w = 0.f;
            *(float4*)(nodeq + 8 * n)     = p;
            *(float4*)(nodeq + 8 * n + 4) = f;
        }
    }
    __syncthreads();
    if (t == 0) {
        unsigned run = 0u;
        for (int b = 0; b < 32; ++b) {
            localBaseS[b] = run;
            cursorLocS[b] = run;
            run += histB[0][b] + histB[1][b] + histB[2][b] + histB[3][b];
        }
    }
    if (t < 32) {
        unsigned h = histB[0][t] + histB[1][t] + histB[2][t] + histB[3][t];
        gBaseS[t] = ((unsigned)t << CAPL) + atomicAdd(&gOff[t], h);
    }
    __syncthreads();
    for (int i = t; i < nedge; i += 1024) {
        unsigned rc = rcbuf[i];
        int b = (int)((rc & 0xFFFFu) >> RSH);
        unsigned p = atomicAdd(&cursorLocS[b], 1u);
        stageRc[p] = rc;
    }
    __syncthreads();
    for (int i = t; i < nedge; i += 1024) {
        unsigned rc = stageRc[i];
        int b = (int)((rc & 0xFFFFu) >> RSH);
        unsigned dst = gBaseS[b] + ((unsigned)i - localBaseS[b]);
        unsigned lim = ((unsigned)(b + 1)) << CAPL;
        if (dst < lim) rcG[dst] = rc;      // capacity guard (statistically impossible to hit)
    }
}

// ---------- pass 2: bucketed gather (unchanged from R8/R9, won) ----------
__global__ __launch_bounds__(512)
void mgather_kernel(const unsigned* __restrict__ rcG,
                    const unsigned* __restrict__ gOff,
                    const float* __restrict__ pos,
                    const float* __restrict__ nodeq,
                    const float* __restrict__ tG,
                    unsigned long long* __restrict__ acc) {
    __shared__ unsigned long long accs[RNODES];   // 16 KB
    __shared__ float posx[RNODES];                // 8 KB
    __shared__ float posy[RNODES];                // 8 KB
    __shared__ float posz[RNODES];                // 8 KB
    __shared__ float tC0[TBL];
    __shared__ float tC1[TBL];
    __shared__ float tC2[TBL];
    __shared__ float tC3[TBL];
    __shared__ float tC4[TBL];
    const int t = threadIdx.x;                    // 0..511
    const int B = blockIdx.x;                     // bucket 0..24
    const int c = blockIdx.y;                     // chunk 0..NCHG-1
    if (t < TBL) {
        tC0[t] = tG[0 * TBL + t];
        tC1[t] = tG[1 * TBL + t];
        tC2[t] = tG[2 * TBL + t];
        tC3[t] = tG[3 * TBL + t];
        tC4[t] = tG[4 * TBL + t];
    }
    const int nb0 = B << RSH;
    for (int j = t; j < RNODES; j += 512) {
        accs[j] = 0ull;
        int n = nb0 + j;
        if (n < N_NODES_C) {
            posx[j] = pos[3 * n + 0];
            posy[j] = pos[3 * n + 1];
            posz[j] = pos[3 * n + 2];
        }
    }
    __syncthreads();

    unsigned cnt = min(gOff[B], (unsigned)(1u << CAPL));   // matches scatter drop guard
    unsigned i0 = (unsigned)(((unsigned long long)cnt * (unsigned)c) / NCHG);
    unsigned i1 = (unsigned)(((unsigned long long)cnt * (unsigned)(c + 1)) / NCHG);
    const unsigned* src = rcG + ((size_t)B << CAPL);

    unsigned i = i0 + t;
    for (; i + 512 < i1; i += 1024) {
        unsigned rcA = src[i];
        unsigned rcB = src[i + 512];
        int rowA = (int)(rcA >> 16), lcA = (int)(rcA & (RNODES - 1));
        int rowB = (int)(rcB >> 16), lcB = (int)(rcB & (RNODES - 1));
        const float4* nrA = (const float4*)(nodeq + ((size_t)rowA << 3));
        const float4* nrB = (const float4*)(nodeq + ((size_t)rowB << 3));
        float4 prA = nrA[0];
        float4 xxA = nrA[1];
        float4 prB = nrB[0];
        float4 xxB = nrB[1];
        float pcxA = posx[lcA], pcyA = posy[lcA], pczA = posz[lcA];
        float pcxB = posx[lcB], pcyB = posy[lcB], pczB = posz[lcB];
        unsigned long long QA = edge_q(prA.x, prA.y, prA.z, xxA, pcxA, pcyA, pczA,
                                       tC0, tC1, tC2, tC3, tC4);
        unsigned long long QB = edge_q(prB.x, prB.y, prB.z, xxB, pcxB, pcyB, pczB,
                                       tC0, tC1, tC2, tC3, tC4);
        atomicAdd(&accs[lcA], QA);
        atomicAdd(&accs[lcB], QB);
    }
    for (; i < i1; i += 512) {
        unsigned rc = src[i];
        int row = (int)(rc >> 16), lc = (int)(rc & (RNODES - 1));
        const float4* nr = (const float4*)(nodeq + ((size_t)row << 3));
        float4 pr = nr[0];
        float4 xx = nr[1];
        unsigned long long Q = edge_q(pr.x, pr.y, pr.z, xx, posx[lc], posy[lc], posz[lc],
                                      tC0, tC1, tC2, tC3, tC4);
        atomicAdd(&accs[lc], Q);
    }
    __syncthreads();
    // flush: coalesced u64 atomics (64 consecutive u64 per wave = 8 lines, L2-merged).
    for (int j = t; j < RNODES; j += 512) {
        unsigned long long v = accs[j];
        int n = nb0 + j;
        if (v && n < N_NODES_C) {
            __hip_atomic_fetch_add(acc + n, v, __ATOMIC_RELAXED, __HIP_MEMORY_SCOPE_AGENT);
        }
    }
}

// ---------- pass 3: decode acc -> float out ----------
__global__ __launch_bounds__(256)
void reduce_unpack(const unsigned long long* __restrict__ acc, float* __restrict__ out) {
    int n = blockIdx.x * 256 + threadIdx.x;
    if (n >= N_NODES_C) return;
    long long T = (long long)acc[n];
    int s0 = (int)(short)(T & 0xFFFF); T = (T - s0) >> 16;
    int s1 = (int)(short)(T & 0xFFFF); T = (T - s1) >> 16;
    int s2 = (int)(short)(T & 0xFFFF); T = (T - s2) >> 16;
    int s3 = (int)T;
    float4 o;
    o.x = (float)s0 * QINV; o.y = (float)s1 * QINV;
    o.z = (float)s2 * QINV; o.w = (float)s3 * QINV;
    *(float4*)(out + 4 * n) = o;
}

// ================= fallback: proven R5 path (tiny ws; full per-edge math) =================
__global__ __launch_bounds__(256)
void init_acc(unsigned long long* __restrict__ acc,
              const void* __restrict__ eidx, int* __restrict__ flag) {
    int i = blockIdx.x * 256 + threadIdx.x;
    if (i < N_NODES_C) acc[i] = 0ull;
    if (blockIdx.x == 0 && threadIdx.x < 64) {
        const long long* p = (const long long*)eidx;
        bool ok = true;
        for (int k = 0; k < 4; ++k) {
            long long v = p[threadIdx.x * 4 + k];
            ok &= (v >= 0 && v < (long long)N_NODES_C);
        }
        unsigned long long m = __ballot(ok);
        if (threadIdx.x == 0) *flag = (m == ~0ull) ? 1 : 0;
    }
}

__global__ __launch_bounds__(256)
void equi_conv_atomic(const float* __restrict__ f1, const float* __restrict__ pos,
                      const float* __restrict__ W1, const float* __restrict__ W2,
                      const void* __restrict__ eidx, const int* __restrict__ flag_p,
                      unsigned long long* __restrict__ acc) {
    __shared__ float w1s[10 * 68];
    const int tid = threadIdx.x;
    for (int i = tid; i < 640; i += 256) w1s[(i >> 6) * 68 + (i & 63)] = W1[i];
    __syncthreads();
    const int e = blockIdx.x * 256 + tid;
    if (e >= N_EDGES_C) return;
    const int is64 = *flag_p;
    int row = load_row(eidx, is64, e);
    int col = load_col(eidx, is64, e);
    int v[4];
    edge_quant(f1, pos, w1s, W2, row, col, v);
    if (v[0] | v[1] | v[2] | v[3]) {
        unsigned long long P = (unsigned long long)((long long)v[0] + ((long long)v[1] << 16)
                             + ((long long)v[2] << 32) + ((long long)v[3] << 48));
        __hip_atomic_fetch_add(acc + col, P, __ATOMIC_RELAXED, __HIP_MEMORY_SCOPE_AGENT);
    }
}

extern "C" void kernel_launch(void* const* d_in, const int* in_sizes, int n_in,
                              void* d_out, int out_size, void* d_ws, size_t ws_size,
                              hipStream_t stream) {
    const float* f1  = (const float*)d_in[0];
    const float* pos = (const float*)d_in[1];
    const float* W1  = (const float*)d_in[2];
    const float* W2  = (const float*)d_in[3];
    const void*  eix = d_in[4];
    float* out = (float*)d_out;

    // ws layout: [rcG 16MB][rcG2 16MB][gOff 128B][gOff2 128B][acc 400KB][tG 5KB][nodeq 1.6MB]
    // rcG2/gOff2: scratch targets for the INSTRUMENTATION duplicate binscatter (R10).
    const size_t offRC  = 0;
    const size_t szRC   = ((size_t)32 << CAPL) * 4;               // 16,777,216 (32 regions padded)
    const size_t offRC2 = offRC + szRC;
    const size_t szRC2  = szRC;                                   // 16,777,216
    const size_t offC   = offRC2 + szRC2;                         // 16-aligned
    const size_t szC    = 32 * 4;                                 // 128
    const size_t offC2  = offC + szC;
    const size_t szC2   = 32 * 4;                                 // 128
    const size_t offA   = offC2 + szC2;                           // 16-aligned
    const size_t szA    = (size_t)N_NODES_C * 8;                  // 400,000
    const size_t offT   = (offA + szA + 15) & ~(size_t)15;
    const size_t szT    = (size_t)5 * TBL * 4;                    // 5,120
    const size_t offQ   = (offT + szT + 15) & ~(size_t)15;
    const size_t szQ    = (size_t)N_NODES_C * 32;                 // 1,600,000
    const size_t need   = offQ + szQ;

    if (ws_size >= need) {
        unsigned*           rcG   = (unsigned*)((char*)d_ws + offRC);
        unsigned*           rcG2  = (unsigned*)((char*)d_ws + offRC2);
        unsigned*           gOff  = (unsigned*)((char*)d_ws + offC);
        unsigned long long* acc   = (unsigned long long*)((char*)d_ws + offA);
        float*              tG    = (float*)((char*)d_ws + offT);
        float*              nodeq = (float*)((char*)d_ws + offQ);
        unsigned*           gOff2 = (unsigned*)((char*)d_ws + offC2);

        // one memset covers gOff + gOff2 + acc (contiguous)
        hipMemsetAsync(gOff, 0, szC + szC2 + szA, stream);
        // INSTRUMENTATION (R10): duplicate binscatter into scratch. nodeq/tG writes are
        // idempotent (identical values); gOff2/rcG2 are never read by the real pipeline.
        // dur_us delta vs R9 (103.5) == one binscatter duration.
        binscatter_kernel<<<NBLK_E3, 1024, 0, stream>>>(f1, pos, W1, W2, eix, gOff2, rcG2, nodeq, tG);
        // real pipeline (unchanged):
        binscatter_kernel<<<NBLK_E3, 1024, 0, stream>>>(f1, pos, W1, W2, eix, gOff, rcG, nodeq, tG);
        mgather_kernel<<<dim3(NREG, NCHG), 512, 0, stream>>>(rcG, gOff, pos, nodeq, tG, acc);
        reduce_unpack<<<NBLK_N, 256, 0, stream>>>(acc, out);
    } else {
        // proven R5 path (needs 400 KB + 4 B)
        unsigned long long* acc = (unsigned long long*)d_ws;
        int* flag = (int*)((char*)d_ws + (size_t)N_NODES_C * 8);
        const int nblk = (N_NODES_C + 255) / 256;
        init_acc<<<nblk, 256, 0, stream>>>(acc, eix, flag);
        equi_conv_atomic<<<(N_EDGES_C + 255) / 256, 256, 0, stream>>>(f1, pos, W1, W2, eix, flag, acc);
        reduce_unpack<<<nblk, 256, 0, stream>>>(acc, out);
    }
}

// Round 11
// 104.149 us; speedup vs baseline: 1.0980x; 1.0980x over previous
//
#include <hip/hip_runtime.h>
#include <math.h>

#define N_NODES_C 50000
#define N_EDGES_C 1600000
#define EPB3 4096
#define NBLK_E3 391                       // ceil(1.6M / 4096); last block has 2560 edges
#define NBLK_N 196                        // (50000+255)>>8
#define TBL 256                           // radial table over r in [0,3]

#define NREG 49                           // col buckets of 1024 nodes (50000/1024 -> 49)
#define NREGP 64                          // padded region count (hist/scan/alloc)
#define RSH 10
#define RNODES 1024
#define CAPL 16                           // 65536 slots/region (mean ~32.6K, sigma ~180)
#define NCHG 16                           // gather chunks per bucket -> 784 blocks

// Quantization q=1/1024 (validated R5: digit-exact u64 accumulation).
#define QSCALE 1024.0f
#define QINV   (1.0f / 1024.0f)

// ---------- per-block dtype detect ----------
__device__ __forceinline__ int detect_is64_block(const void* eidx, int t, int* lds_flag) {
    if (t < 64) {
        const long long* p = (const long long*)eidx;
        bool ok = true;
        for (int k = 0; k < 4; ++k) {
            long long v = p[t * 4 + k];
            ok &= (v >= 0 && v < (long long)N_NODES_C);
        }
        unsigned long long m = __ballot(ok);
        if (t == 0) *lds_flag = (m == ~0ull) ? 1 : 0;
    }
    __syncthreads();
    return *lds_flag;
}

__device__ __forceinline__ int load_col(const void* eidx, int is64, int e) {
    return is64 ? (int)((const long long*)eidx)[N_EDGES_C + e]
                : ((const int*)eidx)[N_EDGES_C + e];
}
__device__ __forceinline__ int load_row(const void* eidx, int is64, int e) {
    return is64 ? (int)((const long long*)eidx)[e]
                : ((const int*)eidx)[e];
}

// ---------- exact edge math (fallback path only; validated R5-R11) ----------
__device__ __forceinline__ void edge_quant(const float* __restrict__ f1,
                                           const float* __restrict__ pos,
                                           const float* __restrict__ w1s,
                                           const float* __restrict__ W2,
                                           int row, int col, int v[4]) {
    v[0] = v[1] = v[2] = v[3] = 0;
    float px = pos[row * 3 + 0] - pos[col * 3 + 0];
    float py = pos[row * 3 + 1] - pos[col * 3 + 1];
    float pz = pos[row * 3 + 2] - pos[col * 3 + 2];
    float r2 = px * px + py * py + pz * pz;
    float r = sqrtf(fmaxf(r2, 1e-12f));
    float inv_r = 1.0f / r;
    float ux = px * inv_r, uy = py * inv_r, uz = pz * inv_r;
    const float SQ3 = 1.7320508075688772f;
    float yv0 = SQ3 * uy, yv1 = SQ3 * uz, yv2 = SQ3 * ux;   // sh perm [1,2,0]

    const float C = 8.433573069075486f;  // 1.14136 * e^2
    float tt = r * (11.0f / 3.0f);
    int k1 = (int)tt;
    float d = tt - (float)k1;
    float e0 = 0.f, e1 = 0.f;
    int b0 = 0, b1 = 0;
    if (k1 >= 1 && k1 <= 10) {
        b0 = k1 - 1;
        e0 = C * __expf(-1.0f / (1.0f + d) - 1.0f / (1.0f - d));
    }
    int k2 = k1 + 1;
    if (k2 <= 10 && d > 0.f) {
        b1 = k2 - 1;
        float d2 = d - 1.0f;
        e1 = C * __expf(-1.0f / (1.0f + d2) - 1.0f / (1.0f - d2));
    }
    if (e0 == 0.f && e1 == 0.f) return;

    const float* r0 = &w1s[b0 * 68];
    const float* r1 = &w1s[b1 * 68];
    float w0 = 0.f, w1a = 0.f, w2a = 0.f, w3 = 0.f, w4 = 0.f;
#pragma unroll
    for (int j = 0; j < 64; j += 4) {
        float4 a = *(const float4*)(r0 + j);
        float4 b = *(const float4*)(r1 + j);
        float h0 = fmaxf(e0 * a.x + e1 * b.x, 0.f);
        float h1 = fmaxf(e0 * a.y + e1 * b.y, 0.f);
        float h2 = fmaxf(e0 * a.z + e1 * b.z, 0.f);
        float h3 = fmaxf(e0 * a.w + e1 * b.w, 0.f);
        w0  += h0 * W2[(j + 0) * 5 + 0] + h1 * W2[(j + 1) * 5 + 0] + h2 * W2[(j + 2) * 5 + 0] + h3 * W2[(j + 3) * 5 + 0];
        w1a += h0 * W2[(j + 0) * 5 + 1] + h1 * W2[(j + 1) * 5 + 1] + h2 * W2[(j + 2) * 5 + 1] + h3 * W2[(j + 3) * 5 + 1];
        w2a += h0 * W2[(j + 0) * 5 + 2] + h1 * W2[(j + 1) * 5 + 2] + h2 * W2[(j + 2) * 5 + 2] + h3 * W2[(j + 3) * 5 + 2];
        w3  += h0 * W2[(j + 0) * 5 + 3] + h1 * W2[(j + 1) * 5 + 3] + h2 * W2[(j + 2) * 5 + 3] + h3 * W2[(j + 3) * 5 + 3];
        w4  += h0 * W2[(j + 0) * 5 + 4] + h1 * W2[(j + 1) * 5 + 4] + h2 * W2[(j + 2) * 5 + 4] + h3 * W2[(j + 3) * 5 + 4];
    }
    const float SC = 0.05590169943749474f;  // sqrt(2/10)/8
    w0 *= SC; w1a *= SC; w2a *= SC; w3 *= SC; w4 *= SC;

    float4 x = *(const float4*)(f1 + row * 4);
    float x0 = x.x, xv0 = x.y, xv1 = x.z, xv2 = x.w;

    const float INV_S3 = 0.5773502691896258f;
    const float INV_S6 = 0.4082482904638631f;
    const float SQH    = 0.7071067811865476f;
    const float INV_SQRT_NN = 0.17677669529663687f;  // 1/sqrt(32)

    float dotxy = xv0 * yv0 + xv1 * yv1 + xv2 * yv2;
    float out0 = SQH * (w0 * x0 + w3 * dotxy * INV_S3) * INV_SQRT_NN;
    float cx0 = xv1 * yv2 - xv2 * yv1;
    float cx1 = xv2 * yv0 - xv0 * yv2;
    float cx2 = xv0 * yv1 - xv1 * yv0;
    float o1 = (w1a * x0 * yv0 * INV_S3 + w2a * xv0 * INV_S3 + w4 * cx0 * INV_S6) * INV_SQRT_NN;
    float o2 = (w1a * x0 * yv1 * INV_S3 + w2a * xv1 * INV_S3 + w4 * cx1 * INV_S6) * INV_SQRT_NN;
    float o3 = (w1a * x0 * yv2 * INV_S3 + w2a * xv2 * INV_S3 + w4 * cx2 * INV_S6) * INV_SQRT_NN;

    v[0] = min(8191, max(-8191, (int)rintf(out0 * QSCALE)));
    v[1] = min(8191, max(-8191, (int)rintf(o1   * QSCALE)));
    v[2] = min(8191, max(-8191, (int)rintf(o2   * QSCALE)));
    v[3] = min(8191, max(-8191, (int)rintf(o3   * QSCALE)));
}

// ---------- edge math -> packed digit sum (identical ops to validated path) ----------
__device__ __forceinline__ unsigned long long edge_q(
        float prx, float pry, float prz, float4 xx,
        float pcx, float pcy, float pcz,
        const float* tC0, const float* tC1, const float* tC2,
        const float* tC3, const float* tC4) {
    float px = prx - pcx;
    float py = pry - pcy;
    float pz = prz - pcz;
    float r2 = px * px + py * py + pz * pz;
    float r = sqrtf(fmaxf(r2, 1e-12f));
    float inv_r = 1.0f / r;
    // unit vector, sh-permuted [1,2,0]: uv = (uy, uz, ux)
    float uv0 = py * inv_r, uv1 = pz * inv_r, uv2 = px * inv_r;

    float ft = fminf(r * (255.0f / 3.0f), 255.0f);
    int idx = min((int)ft, TBL - 2);
    float fr = ft - (float)idx;
    float c0 = fmaf(fr, tC0[idx + 1] - tC0[idx], tC0[idx]);
    float c1 = fmaf(fr, tC1[idx + 1] - tC1[idx], tC1[idx]);
    float c2 = fmaf(fr, tC2[idx + 1] - tC2[idx], tC2[idx]);
    float c3 = fmaf(fr, tC3[idx + 1] - tC3[idx], tC3[idx]);
    float c4 = fmaf(fr, tC4[idx + 1] - tC4[idx], tC4[idx]);

    float x0 = xx.x, xv0 = xx.y, xv1 = xx.z, xv2 = xx.w;

    float dotxy = xv0 * uv0 + xv1 * uv1 + xv2 * uv2;
    float out0 = c0 * x0 + c3 * dotxy;
    float cx0 = xv1 * uv2 - xv2 * uv1;
    float cx1 = xv2 * uv0 - xv0 * uv2;
    float cx2 = xv0 * uv1 - xv1 * uv0;
    float c1x = c1 * x0;
    float o1 = c1x * uv0 + c2 * xv0 + c4 * cx0;
    float o2 = c1x * uv1 + c2 * xv1 + c4 * cx1;
    float o3 = c1x * uv2 + c2 * xv2 + c4 * cx2;

    int v0 = min(8191, max(-8191, (int)rintf(out0 * QSCALE)));
    int v1 = min(8191, max(-8191, (int)rintf(o1 * QSCALE)));
    int v2 = min(8191, max(-8191, (int)rintf(o2 * QSCALE)));
    int v3 = min(8191, max(-8191, (int)rintf(o3 * QSCALE)));

    return (unsigned long long)((long long)v0 + ((long long)v1 << 16)
         + ((long long)v2 << 32) + ((long long)v3 << 48));
}

// ---------- pass 1: MATH-FREE binning scatter into 49 regions of 1024 nodes ----------
__global__ __launch_bounds__(1024)
void binscatter_kernel(const float* __restrict__ f1, const float* __restrict__ pos,
                       const float* __restrict__ W1, const float* __restrict__ W2,
                       const void* __restrict__ eidx,
                       unsigned* __restrict__ gOff,
                       unsigned* __restrict__ rcG,
                       float* __restrict__ nodeq,
                       float* __restrict__ tG) {
    __shared__ unsigned rcbuf[EPB3];         // 16 KB
    __shared__ unsigned stageRc[EPB3];       // 16 KB; first 2.7 KB aliased as w1s (block 0 only)
    __shared__ unsigned histB[4][NREGP];     // 4-bank histogram, 1 KB
    __shared__ unsigned gBaseS[NREGP];
    __shared__ unsigned localBaseS[NREGP];
    __shared__ unsigned cursorLocS[NREGP];
    __shared__ int flag_s;
    const int t = threadIdx.x;
    float* w1s = (float*)stageRc;            // safe: table build done before phase C writes stageRc
    if (blockIdx.x == 0) {
        for (int i = t; i < 640; i += 1024) w1s[(i >> 6) * 68 + (i & 63)] = W1[i];
    }
    if (t < 256) histB[t >> 6][t & 63] = 0u;
    const int is64 = detect_is64_block(eidx, t, &flag_s);  // includes __syncthreads

    if (blockIdx.x == 0 && t < TBL) {
        // ---- build table entry t (validated R12, bit-identical) ----
        float tt = (float)t * (11.0f / 255.0f);
        int k1 = (int)tt;
        float d = tt - (float)k1;
        const float C = 8.433573069075486f;  // 1.14136 * e^2
        float e0 = 0.f, e1 = 0.f;
        int b0 = 0, b1 = 0;
        if (k1 >= 1 && k1 <= 10) {
            b0 = k1 - 1;
            e0 = C * __expf(-1.0f / (1.0f + d) - 1.0f / (1.0f - d));
        }
        int k2 = k1 + 1;
        if (k2 <= 10 && d > 0.f) {
            b1 = k2 - 1;
            float d2 = d - 1.0f;
            e1 = C * __expf(-1.0f / (1.0f + d2) - 1.0f / (1.0f - d2));
        }
        float w0 = 0.f, w1 = 0.f, w2 = 0.f, w3 = 0.f, w4 = 0.f;
        const float* r0 = &w1s[b0 * 68];
        const float* r1 = &w1s[b1 * 68];
#pragma unroll
        for (int j = 0; j < 64; j += 4) {
            float4 a = *(const float4*)(r0 + j);
            float4 b = *(const float4*)(r1 + j);
            float h0 = fmaxf(e0 * a.x + e1 * b.x, 0.f);
            float h1 = fmaxf(e0 * a.y + e1 * b.y, 0.f);
            float h2 = fmaxf(e0 * a.z + e1 * b.z, 0.f);
            float h3 = fmaxf(e0 * a.w + e1 * b.w, 0.f);
            w0 += h0 * W2[(j + 0) * 5 + 0] + h1 * W2[(j + 1) * 5 + 0] + h2 * W2[(j + 2) * 5 + 0] + h3 * W2[(j + 3) * 5 + 0];
            w1 += h0 * W2[(j + 0) * 5 + 1] + h1 * W2[(j + 1) * 5 + 1] + h2 * W2[(j + 2) * 5 + 1] + h3 * W2[(j + 3) * 5 + 1];
            w2 += h0 * W2[(j + 0) * 5 + 2] + h1 * W2[(j + 1) * 5 + 2] + h2 * W2[(j + 2) * 5 + 2] + h3 * W2[(j + 3) * 5 + 2];
            w3 += h0 * W2[(j + 0) * 5 + 3] + h1 * W2[(j + 1) * 5 + 3] + h2 * W2[(j + 2) * 5 + 3] + h3 * W2[(j + 3) * 5 + 3];
            w4 += h0 * W2[(j + 0) * 5 + 4] + h1 * W2[(j + 1) * 5 + 4] + h2 * W2[(j + 2) * 5 + 4] + h3 * W2[(j + 3) * 5 + 4];
        }
        const float SC  = 0.05590169943749474f;   // sqrt(2/10)/8
        const float ISN = 0.17677669529663687f;   // 1/sqrt(32)
        const float SQH = 0.7071067811865476f;
        const float INV_S3 = 0.5773502691896258f;
        const float INV_S6 = 0.4082482904638631f;
        const float SQ3 = 1.7320508075688772f;
        float base = SC * ISN;
        tG[0 * TBL + t] = SQH * base * w0;
        tG[1 * TBL + t] = base * w1;
        tG[2 * TBL + t] = INV_S3 * base * w2;
        tG[3 * TBL + t] = SQH * base * w3;
        tG[4 * TBL + t] = INV_S6 * SQ3 * base * w4;
    }

    const int e0b = blockIdx.x * EPB3;
    const int nedge = min(EPB3, N_EDGES_C - e0b);  // 4096 or 2560
    const int hb = (t >> 6) & 3;
    for (int i = t; i < nedge; i += 1024) {
        int row = load_row(eidx, is64, e0b + i);
        int col = load_col(eidx, is64, e0b + i);
        rcbuf[i] = ((unsigned)row << 16) | (unsigned)col;
        atomicAdd(&histB[hb][col >> RSH], 1u);
    }
    {
        int n = blockIdx.x * 1024 + t;
        if (n < N_NODES_C) {
            float4 f = *(const float4*)(f1 + 4 * n);
            float4 p;
            p.x = pos[3 * n + 0];
            p.y = pos[3 * n + 1];
            p.z = pos[3 * n + 2];
            p.w = 0.f;
            *(float4*)(nodeq + 8 * n)     = p;
            *(float4*)(nodeq + 8 * n + 4) = f;
        }
    }
    __syncthreads();
    if (t == 0) {
        unsigned run = 0u;
        for (int b = 0; b < NREGP; ++b) {
            localBaseS[b] = run;
            cursorLocS[b] = run;
            run += histB[0][b] + histB[1][b] + histB[2][b] + histB[3][b];
        }
    }
    if (t < NREGP) {
        unsigned h = histB[0][t] + histB[1][t] + histB[2][t] + histB[3][t];
        gBaseS[t] = ((unsigned)t << CAPL) + atomicAdd(&gOff[t], h);
    }
    __syncthreads();
    for (int i = t; i < nedge; i += 1024) {
        unsigned rc = rcbuf[i];
        int b = (int)((rc & 0xFFFFu) >> RSH);
        unsigned p = atomicAdd(&cursorLocS[b], 1u);
        stageRc[p] = rc;
    }
    __syncthreads();
    // coalesced run-wise stream-out (runs avg ~84 packets)
    for (int i = t; i < nedge; i += 1024) {
        unsigned rc = stageRc[i];
        int b = (int)((rc & 0xFFFFu) >> RSH);
        unsigned dst = gBaseS[b] + ((unsigned)i - localBaseS[b]);
        unsigned lim = ((unsigned)(b + 1)) << CAPL;
        if (dst < lim) rcG[dst] = rc;      // capacity guard (statistically impossible to hit)
    }
}

// ---------- pass 2: bucketed gather v2 — small LDS (25 KB), 256 thr, batch-4 MLP ----------
// Theory (R10 readout): mgather is L2-latency-bound on the divergent nodeq[row] load;
// throughput = aggregate outstanding loads / latency. v2 raises waves/CU (25 KB LDS,
// 784 all-resident blocks) and loads-in-flight/wave (batch-4: 4 rc + 8 float4 loads
// issued before any math). Flush atomics drop to 784x1024 ~= 800K coalesced u64.
__global__ __launch_bounds__(256)
void mgather_kernel(const unsigned* __restrict__ rcG,
                    const unsigned* __restrict__ gOff,
                    const float* __restrict__ pos,
                    const float* __restrict__ nodeq,
                    const float* __restrict__ tG,
                    unsigned long long* __restrict__ acc) {
    __shared__ unsigned long long accs[RNODES];   // 8 KB
    __shared__ float posx[RNODES];                // 4 KB
    __shared__ float posy[RNODES];                // 4 KB
    __shared__ float posz[RNODES];                // 4 KB
    __shared__ float tC0[TBL];
    __shared__ float tC1[TBL];
    __shared__ float tC2[TBL];
    __shared__ float tC3[TBL];
    __shared__ float tC4[TBL];
    const int t = threadIdx.x;                    // 0..255
    const int B = blockIdx.x;                     // bucket 0..48
    const int c = blockIdx.y;                     // chunk 0..NCHG-1
    tC0[t] = tG[0 * TBL + t];
    tC1[t] = tG[1 * TBL + t];
    tC2[t] = tG[2 * TBL + t];
    tC3[t] = tG[3 * TBL + t];
    tC4[t] = tG[4 * TBL + t];
    const int nb0 = B << RSH;
    for (int j = t; j < RNODES; j += 256) {
        accs[j] = 0ull;
        int n = nb0 + j;
        if (n < N_NODES_C) {
            posx[j] = pos[3 * n + 0];
            posy[j] = pos[3 * n + 1];
            posz[j] = pos[3 * n + 2];
        }
    }
    __syncthreads();

    unsigned cnt = min(gOff[B], (unsigned)(1u << CAPL));   // matches scatter drop guard
    unsigned i0 = (unsigned)(((unsigned long long)cnt * (unsigned)c) / NCHG);
    unsigned i1 = (unsigned)(((unsigned long long)cnt * (unsigned)(c + 1)) / NCHG);
    const unsigned* src = rcG + ((size_t)B << CAPL);

    // batch-4: all rc reads + all divergent nodeq loads issued before any math.
    for (unsigned ib = i0 + t; ib < i1; ib += 1024) {
        unsigned ia = ib + 256, ic = ib + 512, id = ib + 768;
        bool va = ia < i1, vb = ic < i1, vc = id < i1;
        unsigned rc0 = src[ib];
        unsigned rc1 = va ? src[ia] : rc0;     // sentinel: duplicate edge 0 (unaccumulated)
        unsigned rc2 = vb ? src[ic] : rc0;
        unsigned rc3 = vc ? src[id] : rc0;
        int row0 = (int)(rc0 >> 16), lc0 = (int)(rc0 & (RNODES - 1));
        int row1 = (int)(rc1 >> 16), lc1 = (int)(rc1 & (RNODES - 1));
        int row2 = (int)(rc2 >> 16), lc2 = (int)(rc2 & (RNODES - 1));
        int row3 = (int)(rc3 >> 16), lc3 = (int)(rc3 & (RNODES - 1));
        const float4* nr0 = (const float4*)(nodeq + ((size_t)row0 << 3));
        const float4* nr1 = (const float4*)(nodeq + ((size_t)row1 << 3));
        const float4* nr2 = (const float4*)(nodeq + ((size_t)row2 << 3));
        const float4* nr3 = (const float4*)(nodeq + ((size_t)row3 << 3));
        float4 pr0 = nr0[0], xx0 = nr0[1];
        float4 pr1 = nr1[0], xx1 = nr1[1];
        float4 pr2 = nr2[0], xx2 = nr2[1];
        float4 pr3 = nr3[0], xx3 = nr3[1];

        unsigned long long Q0 = edge_q(pr0.x, pr0.y, pr0.z, xx0, posx[lc0], posy[lc0], posz[lc0],
                                       tC0, tC1, tC2, tC3, tC4);
        unsigned long long Q1 = edge_q(pr1.x, pr1.y, pr1.z, xx1, posx[lc1], posy[lc1], posz[lc1],
                                       tC0, tC1, tC2, tC3, tC4);
        unsigned long long Q2 = edge_q(pr2.x, pr2.y, pr2.z, xx2, posx[lc2], posy[lc2], posz[lc2],
                                       tC0, tC1, tC2, tC3, tC4);
        unsigned long long Q3 = edge_q(pr3.x, pr3.y, pr3.z, xx3, posx[lc3], posy[lc3], posz[lc3],
                                       tC0, tC1, tC2, tC3, tC4);
        atomicAdd(&accs[lc0], Q0);
        if (va) atomicAdd(&accs[lc1], Q1);
        if (vb) atomicAdd(&accs[lc2], Q2);
        if (vc) atomicAdd(&accs[lc3], Q3);
    }
    __syncthreads();
    // flush: coalesced u64 atomics (64 consecutive u64 per wave = 8 lines, L2-merged).
    for (int j = t; j < RNODES; j += 256) {
        unsigned long long v = accs[j];
        int n = nb0 + j;
        if (v && n < N_NODES_C) {
            __hip_atomic_fetch_add(acc + n, v, __ATOMIC_RELAXED, __HIP_MEMORY_SCOPE_AGENT);
        }
    }
}

// ---------- pass 3: decode acc -> float out ----------
__global__ __launch_bounds__(256)
void reduce_unpack(const unsigned long long* __restrict__ acc, float* __restrict__ out) {
    int n = blockIdx.x * 256 + threadIdx.x;
    if (n >= N_NODES_C) return;
    long long T = (long long)acc[n];
    int s0 = (int)(short)(T & 0xFFFF); T = (T - s0) >> 16;
    int s1 = (int)(short)(T & 0xFFFF); T = (T - s1) >> 16;
    int s2 = (int)(short)(T & 0xFFFF); T = (T - s2) >> 16;
    int s3 = (int)T;
    float4 o;
    o.x = (float)s0 * QINV; o.y = (float)s1 * QINV;
    o.z = (float)s2 * QINV; o.w = (float)s3 * QINV;
    *(float4*)(out + 4 * n) = o;
}

// ================= fallback: proven R5 path (tiny ws; full per-edge math) =================
__global__ __launch_bounds__(256)
void init_acc(unsigned long long* __restrict__ acc,
              const void* __restrict__ eidx, int* __restrict__ flag) {
    int i = blockIdx.x * 256 + threadIdx.x;
    if (i < N_NODES_C) acc[i] = 0ull;
    if (blockIdx.x == 0 && threadIdx.x < 64) {
        const long long* p = (const long long*)eidx;
        bool ok = true;
        for (int k = 0; k < 4; ++k) {
            long long v = p[threadIdx.x * 4 + k];
            ok &= (v >= 0 && v < (long long)N_NODES_C);
        }
        unsigned long long m = __ballot(ok);
        if (threadIdx.x == 0) *flag = (m == ~0ull) ? 1 : 0;
    }
}

__global__ __launch_bounds__(256)
void equi_conv_atomic(const float* __restrict__ f1, const float* __restrict__ pos,
                      const float* __restrict__ W1, const float* __restrict__ W2,
                      const void* __restrict__ eidx, const int* __restrict__ flag_p,
                      unsigned long long* __restrict__ acc) {
    __shared__ float w1s[10 * 68];
    const int tid = threadIdx.x;
    for (int i = tid; i < 640; i += 256) w1s[(i >> 6) * 68 + (i & 63)] = W1[i];
    __syncthreads();
    const int e = blockIdx.x * 256 + tid;
    if (e >= N_EDGES_C) return;
    const int is64 = *flag_p;
    int row = load_row(eidx, is64, e);
    int col = load_col(eidx, is64, e);
    int v[4];
    edge_quant(f1, pos, w1s, W2, row, col, v);
    if (v[0] | v[1] | v[2] | v[3]) {
        unsigned long long P = (unsigned long long)((long long)v[0] + ((long long)v[1] << 16)
                             + ((long long)v[2] << 32) + ((long long)v[3] << 48));
        __hip_atomic_fetch_add(acc + col, P, __ATOMIC_RELAXED, __HIP_MEMORY_SCOPE_AGENT);
    }
}

extern "C" void kernel_launch(void* const* d_in, const int* in_sizes, int n_in,
                              void* d_out, int out_size, void* d_ws, size_t ws_size,
                              hipStream_t stream) {
    const float* f1  = (const float*)d_in[0];
    const float* pos = (const float*)d_in[1];
    const float* W1  = (const float*)d_in[2];
    const float* W2  = (const float*)d_in[3];
    const void*  eix = d_in[4];
    float* out = (float*)d_out;

    // ws layout: [rcG 16MB][gOff 256B][acc 400KB][tG 5KB][nodeq 1.6MB] ~= 18.8MB
    const size_t offRC = 0;
    const size_t szRC  = ((size_t)NREGP << CAPL) * 4;             // 16,777,216 (64 regions padded)
    const size_t offC  = offRC + szRC;                            // 16-aligned
    const size_t szC   = NREGP * 4;                               // 256
    const size_t offA  = offC + szC;                              // 16-aligned
    const size_t szA   = (size_t)N_NODES_C * 8;                   // 400,000
    const size_t offT  = (offA + szA + 15) & ~(size_t)15;
    const size_t szT   = (size_t)5 * TBL * 4;                     // 5,120
    const size_t offQ  = (offT + szT + 15) & ~(size_t)15;
    const size_t szQ   = (size_t)N_NODES_C * 32;                  // 1,600,000
    const size_t need  = offQ + szQ;

    if (ws_size >= need) {
        unsigned*           rcG   = (unsigned*)((char*)d_ws + offRC);
        unsigned*           gOff  = (unsigned*)((char*)d_ws + offC);
        unsigned long long* acc   = (unsigned long long*)((char*)d_ws + offA);
        float*              tG    = (float*)((char*)d_ws + offT);
        float*              nodeq = (float*)((char*)d_ws + offQ);

        // one memset covers gOff + acc (contiguous)
        hipMemsetAsync(gOff, 0, szC + szA, stream);
        binscatter_kernel<<<NBLK_E3, 1024, 0, stream>>>(f1, pos, W1, W2, eix, gOff, rcG, nodeq, tG);
        mgather_kernel<<<dim3(NREG, NCHG), 256, 0, stream>>>(rcG, gOff, pos, nodeq, tG, acc);
        reduce_unpack<<<NBLK_N, 256, 0, stream>>>(acc, out);
    } else {
        // proven R5 path (needs 400 KB + 4 B)
        unsigned long long* acc = (unsigned long long*)d_ws;
        int* flag = (int*)((char*)d_ws + (size_t)N_NODES_C * 8);
        const int nblk = (N_NODES_C + 255) / 256;
        init_acc<<<nblk, 256, 0, stream>>>(acc, eix, flag);
        equi_conv_atomic<<<(N_EDGES_C + 255) / 256, 256, 0, stream>>>(f1, pos, W1, W2, eix, flag, acc);
        reduce_unpack<<<nblk, 256, 0, stream>>>(acc, out);
    }
}